// Round 12
// baseline (574.487 us; speedup 1.0000x reference)
//
#include <hip/hip_runtime.h>
#include <hip/hip_bf16.h>
#include <stdint.h>

#define VOCAB 30000
#define EMBED 256
#define HID   128
#define BB    256
#define TT    512
#define G4    512        // gate columns per direction
#define GWH   1024       // f16 columns in EW2 ([dir][u][g] packed)

typedef _Float16 f16x8 __attribute__((ext_vector_type(8)));
typedef _Float16 f16x4 __attribute__((ext_vector_type(4)));
typedef float    f32x4 __attribute__((ext_vector_type(4)));

// gate scales folded into EW and U at build time:
//   i,f,o : z' = -log2(e)  * z   -> sigm = rcp(1 + exp2(z'))
//   g     : z' = +2log2(e) * z   -> tanh = 1 - 2*rcp(1 + exp2(z'))
#define S_IFO (-1.4426950408889634f)
#define S_G   ( 2.8853900817779268f)

__device__ __forceinline__ float fexp2(float x){
#if __has_builtin(__builtin_amdgcn_exp2f)
  return __builtin_amdgcn_exp2f(x);
#else
  return exp2f(x);
#endif
}
__device__ __forceinline__ float frcp(float x){
#if __has_builtin(__builtin_amdgcn_rcpf)
  return __builtin_amdgcn_rcpf(x);
#else
  return 1.0f/x;
#endif
}
__device__ __forceinline__ float sigm_p(float zp){ return frcp(1.0f + fexp2(zp)); }
__device__ __forceinline__ float tanh_p(float zp){ return 1.0f - 2.0f*frcp(1.0f + fexp2(zp)); }
__device__ __forceinline__ float tanh_rt(float x){ return 1.0f - 2.0f*frcp(1.0f + fexp2(S_G*x)); }

// ---------------------------------------------------------------------------
// Kernel 1: EW2[v][dirc*512 + u*4 + g] = f16( gsc[g] * (emb[v]@Wcol + b) )
// ---------------------------------------------------------------------------
__global__ __launch_bounds__(256, 4) void embw_mfma(
    const float* __restrict__ emb,
    const float* __restrict__ Wf, const float* __restrict__ Wb,
    const float* __restrict__ bf, const float* __restrict__ bb,
    _Float16* __restrict__ EW)
{
  __shared__ _Float16 As[64*EMBED];   // 32 KB
  const int tid  = threadIdx.x;
  const int l    = tid & 63;
  const int w    = tid >> 6;
  const int r0   = blockIdx.x * 64;
  const int dirc = blockIdx.y >> 3;
  const int u0   = (blockIdx.y & 7) * 16;
  const int nr   = min(64, VOCAB - r0);

  const float4* asrc = (const float4*)(emb + (size_t)r0*EMBED);
  for (int i = tid; i < nr*(EMBED/4); i += 256){
    float4 v = asrc[i];
    const int row = i >> 6;
    const int kc  = (i & 63) * 4;
    const int ks  = kc ^ ((row & 7) << 3);
    _Float16* dst = &As[row*EMBED + ks];
    dst[0]=(_Float16)v.x; dst[1]=(_Float16)v.y;
    dst[2]=(_Float16)v.z; dst[3]=(_Float16)v.w;
  }
  __syncthreads();

  const int cl = w*16 + (l & 15);
  const int ul = cl >> 2;             // 0..15
  const int g  = cl & 3;              // gate
  const int cg = g*128 + u0 + ul;     // original column in [0,512)
  const float* Wsrc = (dirc ? Wb : Wf) + cg;
  const int kg = (l >> 4) * 8;

  f32x4 acc[4] = {{0,0,0,0},{0,0,0,0},{0,0,0,0},{0,0,0,0}};

  for (int kk = 0; kk < EMBED/32; ++kk){
    const int kb = kk*32 + kg;
    f16x8 bfrag;
    #pragma unroll
    for (int j = 0; j < 8; ++j)
      bfrag[j] = (_Float16)Wsrc[(size_t)(kb + j)*G4];
    #pragma unroll
    for (int m = 0; m < 4; ++m){
      const int row = m*16 + (l & 15);
      const int ks  = kb ^ ((row & 7) << 3);
      f16x8 afrag = *(const f16x8*)&As[row*EMBED + ks];
      acc[m] = __builtin_amdgcn_mfma_f32_16x16x32_f16(afrag, bfrag, acc[m], 0, 0, 0);
    }
  }

  const float bv  = (dirc ? bb : bf)[cg];
  const float gsc = (g == 2) ? S_G : S_IFO;
  const int   co  = dirc*512 + (u0 + ul)*4 + g;    // f16 col in EW2
  #pragma unroll
  for (int m = 0; m < 4; ++m){
    #pragma unroll
    for (int r = 0; r < 4; ++r){
      const int vrow = r0 + m*16 + (l >> 4)*4 + r;
      if (vrow < VOCAB)
        EW[(size_t)vrow*GWH + co] = (_Float16)((acc[m][r] + bv) * gsc);
    }
  }
}

// ---------------------------------------------------------------------------
// Kernel 2: dir-paired phase pipeline. Block = batch b, BOTH dirs (grid 256).
// Phase A: MFMA fw@i || gates bw@(i-1);  Phase B: MFMA bw@i || gates fw@i.
// Gate chain of one dir hides under the other dir's MFMA. Single h buffer
// per dir (write/read always barrier-separated). A-operand = broadcast h.
// U both dirs register-resident (128 VGPR). Persistent accs, pre-scaled acts.
// ---------------------------------------------------------------------------
__global__ __launch_bounds__(512, 2) void lstm_dp(
    const int*      __restrict__ tokens,
    const _Float16* __restrict__ EW,
    const float*    __restrict__ Ufw, const float* __restrict__ Ubw,
    float* __restrict__ out)
{
  __shared__ _Float16 h_lds[2][160];   // [dir][unit], 128 used + pad
  __shared__ int      tok_lds[TT];     // 2 KB

  const int tid = threadIdx.x;
  const int l   = tid & 63;
  const int w   = tid >> 6;            // wave 0..7
  const int lr  = l & 15;
  const int hi  = l >> 4;
  const int b   = blockIdx.x;

  if (tid < 320) ((_Float16*)h_lds)[tid] = (_Float16)0.f;
  if (tid < TT)  tok_lds[tid] = tokens[(size_t)b*TT + tid];
  __syncthreads();

  // ---- resident U fragments, BOTH dirs (pre-scaled): 128 VGPRs ----
  f16x8 ub[2][4][4];
  #pragma unroll
  for (int d = 0; d < 2; ++d){
    const float* U = d ? Ubw : Ufw;
    #pragma unroll
    for (int kt = 0; kt < 4; ++kt){
      #pragma unroll
      for (int g = 0; g < 4; ++g){
        const int   col = g*128 + w*16 + lr;
        const float gs  = (g == 2) ? S_G : S_IFO;
        f16x8 f;
        #pragma unroll
        for (int j = 0; j < 8; ++j)
          f[j] = (_Float16)(U[(size_t)(kt*32 + hi*8 + j)*G4 + col] * gs);
        ub[d][kt][g] = f;
      }
    }
  }

  const bool act = (l < 16);
  const int  u   = w*16 + lr;          // act lanes: lr == l

  float cF = 0.f, cB = 0.f, hFv = 0.f, hBv = 0.f;
  const _Float16* eb0 = EW +       u*4;      // fw base
  const _Float16* eb1 = EW + 512 + u*4;      // bw base

  // address of xw for (dir, step S), clamped
  #define ADDR_F(S) (eb0 + (size_t)tok_lds[(S) < TT ? (S) : TT-1]*GWH)
  #define ADDR_B(S) (eb1 + (size_t)tok_lds[(S) < TT ? TT-1-(S) : 0]*GWH)

  // persistent accumulators (broadcast-A -> all rows equal; row 0 read)
  f32x4 aF[4], aB[4];
  #pragma unroll
  for (int g = 0; g < 4; ++g){ aF[g]=(f32x4){0,0,0,0}; aB[g]=(f32x4){0,0,0,0}; }

  f16x4 xwF = {0,0,0,0}, xwB = {0,0,0,0};
  const _Float16 *adF = eb0, *adB = eb1;
  if (act){
    xwF = *(const f16x4*)ADDR_F(0);
    xwB = *(const f16x4*)ADDR_B(0);
    adF = ADDR_F(1);
    adB = ADDR_B(1);
    #pragma unroll
    for (int g = 0; g < 4; ++g){ aF[g][0] = (float)xwF[g]; aB[g][0] = (float)xwB[g]; }
    xwF = *(const f16x4*)adF;  adF = ADDR_F(2);   // xw(fw,1), addr(fw,2)
    xwB = *(const f16x4*)adB;  adB = ADDR_B(2);   // xw(bw,1), addr(bw,2)
  }

  #define MFMA_PH(ACC, D)                                                    \
  { f16x8 ha[4];                                                             \
    _Pragma("unroll")                                                        \
    for (int kt = 0; kt < 4; ++kt)                                           \
      ha[kt] = *(const f16x8*)&h_lds[D][kt*32 + hi*8];                       \
    _Pragma("unroll")                                                        \
    for (int kt = 0; kt < 4; ++kt){                                          \
      _Pragma("unroll")                                                      \
      for (int g = 0; g < 4; ++g)                                            \
        ACC[g] = __builtin_amdgcn_mfma_f32_16x16x32_f16(ha[kt], ub[D][kt][g], ACC[g], 0,0,0); \
    } }

  // gates for dir DIRC at step with time T_; then re-arm ACC with next xw
  #define GATE_PH(ACC, XW, AD, ADDR_M, CREG, HFIN, SNEXT, T_, DIRC)          \
  if (act){                                                                  \
    const float si = sigm_p(ACC[0][0]);                                      \
    const float sf = sigm_p(ACC[1][0]);                                      \
    const float tg = tanh_p(ACC[2][0]);                                      \
    const float so = sigm_p(ACC[3][0]);                                      \
    const float cn = sf*CREG + si*tg;                                        \
    CREG = cn;                                                               \
    const float hh = so*tanh_rt(cn);                                         \
    HFIN = hh;                                                               \
    h_lds[DIRC][u] = (_Float16)hh;                                           \
    out[((size_t)b*TT + (T_))*(2*HID) + (size_t)(DIRC)*HID + u] = hh;        \
    _Pragma("unroll")                                                        \
    for (int g = 0; g < 4; ++g) ACC[g][0] = (float)XW[g];                    \
    XW = *(const f16x4*)AD;                                                  \
    AD = ADDR_M(SNEXT);                                                      \
  }

  for (int i = 0; i < TT; ++i){
    // ---- phase A: gates bw@(i-1) || MFMA fw@i ----
    if (i > 0){
      GATE_PH(aB, xwB, adB, ADDR_B, cB, hBv, i+2, (TT-1-(i-1)), 1)
    }
    MFMA_PH(aF, 0)
    asm volatile("s_waitcnt lgkmcnt(0)" ::: "memory");
    __builtin_amdgcn_s_barrier();

    // ---- phase B: gates fw@i || MFMA bw@i ----
    GATE_PH(aF, xwF, adF, ADDR_F, cF, hFv, i+3, i, 0)
    MFMA_PH(aB, 1)
    asm volatile("s_waitcnt lgkmcnt(0)" ::: "memory");
    __builtin_amdgcn_s_barrier();
  }

  // ---- epilogue: gates bw@(TT-1), t = 0 ----
  if (act){
    const float si = sigm_p(aB[0][0]);
    const float sf = sigm_p(aB[1][0]);
    const float tg = tanh_p(aB[2][0]);
    const float so = sigm_p(aB[3][0]);
    const float cn = sf*cB + si*tg;
    cB = cn;
    const float hh = so*tanh_rt(cn);
    hBv = hh;
    out[((size_t)b*TT + 0)*(2*HID) + HID + u] = hh;
  }

  #undef GATE_PH
  #undef MFMA_PH
  #undef ADDR_F
  #undef ADDR_B

  // ---- final h_T / c_T ----
  if (act){
    const size_t O1  = (size_t)BB*TT*(2*HID);
    const size_t idx = (size_t)b*HID + u;
    out[O1                        + idx] = hFv;
    out[O1 +   (size_t)BB*HID     + idx] = cF;
    out[O1 + 2*(size_t)BB*HID     + idx] = hBv;
    out[O1 + 3*(size_t)BB*HID     + idx] = cB;
  }
}

extern "C" void kernel_launch(void* const* d_in, const int* in_sizes, int n_in,
                              void* d_out, int out_size, void* d_ws, size_t ws_size,
                              hipStream_t stream)
{
  const int*   tokens = (const int*)  d_in[0];
  const float* emb    = (const float*)d_in[1];
  const float* Wf     = (const float*)d_in[2];
  const float* Ufw    = (const float*)d_in[3];
  const float* bf     = (const float*)d_in[4];
  const float* Wb     = (const float*)d_in[5];
  const float* Ubw    = (const float*)d_in[6];
  const float* bb     = (const float*)d_in[7];
  float* out = (float*)d_out;
  _Float16* EW = (_Float16*)d_ws;     // 30000 x 1024 f16 = 61.44 MB

  embw_mfma<<<dim3((VOCAB + 63)/64, 16), 256, 0, stream>>>(emb, Wf, Wb, bf, bb, EW);
  lstm_dp<<<BB, 512, 0, stream>>>(tokens, EW, Ufw, Ubw, out);
}